// Round 4
// baseline (4590.177 us; speedup 1.0000x reference)
//
#include <hip/hip_runtime.h>

// ---------------------------------------------------------------------------
// SubtasksRecurrence: T=128 sequential steps, B=256 independent rows.
// R4: 768-thread seq blocks (12 waves). The gi/gh matvecs stream ONE packed
//     float2 array WT2[k][col]=(W_ih[col][k],W_hh[col][k]) — 1 coalesced load
//     + 1 LDS broadcast + 2 FMA per k per thread. W_f tail / W_pi / W_beta
//     tail cached in LDS (~94 KB). C1 row + gumbel tables prefetched under
//     the stream. Zero grid sync (batch-parallel decomposition from R3).
// All accumulation orders for sampled quantities bit-match R3 (which passed).
// ---------------------------------------------------------------------------

#define RNG_PARTITIONABLE 1

#define T_STEPS 128
#define B_ROWS  256
#define TOT     338
#define CONV    4096
#define LDWF    4161   // W_f row stride (CONV + 2S + 1)
#define LDWB    4128   // W_beta row stride (CONV + S)

// ------------------------------- threefry ----------------------------------
__device__ __forceinline__ void tf2x32(unsigned k0, unsigned k1, unsigned c0, unsigned c1,
                                       unsigned &o0, unsigned &o1) {
  const unsigned ks2 = k0 ^ k1 ^ 0x1BD11BDAu;
  unsigned x0 = c0 + k0;
  unsigned x1 = c1 + k1;
#define TFR(r) { x0 += x1; x1 = (x1 << (r)) | (x1 >> (32 - (r))); x1 ^= x0; }
  TFR(13) TFR(15) TFR(26) TFR(6)
  x0 += k1; x1 += ks2 + 1u;
  TFR(17) TFR(29) TFR(16) TFR(24)
  x0 += ks2; x1 += k0 + 2u;
  TFR(13) TFR(15) TFR(26) TFR(6)
  x0 += k0; x1 += k1 + 3u;
  TFR(17) TFR(29) TFR(16) TFR(24)
  x0 += k1; x1 += ks2 + 4u;
  TFR(13) TFR(15) TFR(26) TFR(6)
  x0 += ks2; x1 += k0 + 5u;
#undef TFR
  o0 = x0; o1 = x1;
}

__device__ __forceinline__ void rng_key(unsigned j, unsigned &k0, unsigned &k1) {
#if RNG_PARTITIONABLE
  tf2x32(0u, 42u, 0u, j, k0, k1);
#else
  unsigned w[2];
  for (int q = 0; q < 2; ++q) {
    unsigned i = 2u*j + (unsigned)q, a, b;
    if (i < 256u) { tf2x32(0u, 42u, i, 256u + i, a, b); w[q] = a; }
    else          { tf2x32(0u, 42u, i - 256u, i, a, b); w[q] = b; }
  }
  k0 = w[0]; k1 = w[1];
#endif
}

__device__ __forceinline__ unsigned rng_bits(unsigned k0, unsigned k1, unsigned idx, unsigned total) {
#if RNG_PARTITIONABLE
  unsigned o0, o1;
  tf2x32(k0, k1, 0u, idx, o0, o1);
  return o0 ^ o1;
#else
  unsigned half = total >> 1, o0, o1;
  if (idx < half) { tf2x32(k0, k1, idx, half + idx, o0, o1); return o0; }
  else            { tf2x32(k0, k1, idx - half, idx, o0, o1); return o1; }
#endif
}

__device__ __forceinline__ float gumbel_from_bits(unsigned bits) {
  float u0 = __uint_as_float(0x3f800000u | (bits >> 9)) - 1.0f;
  float u  = fmaxf(u0, 1.17549435e-38f);
  return -logf(-logf(u));
}

// ------------------------------ small kernels ------------------------------
__global__ __launch_bounds__(256) void rng_k(float* __restrict__ ggum, float* __restrict__ bgum) {
  unsigned tid = blockIdx.x * 256u + threadIdx.x;
  const unsigned NG = T_STEPS * B_ROWS * 16;
  const unsigned NB = T_STEPS * B_ROWS * 2;
  if (tid < NG) {
    unsigned t = tid / (B_ROWS * 16);
    unsigned i = tid % (B_ROWS * 16);
    unsigned k0, k1; rng_key(2u * t, k0, k1);
    ggum[tid] = gumbel_from_bits(rng_bits(k0, k1, i, B_ROWS * 16));
  } else if (tid < NG + NB) {
    unsigned q = tid - NG;
    unsigned t = q / (B_ROWS * 2);
    unsigned i = q % (B_ROWS * 2);
    unsigned k0, k1; rng_key(2u * t + 1u, k0, k1);
    bgum[q] = gumbel_from_bits(rng_bits(k0, k1, i, B_ROWS * 2));
  }
}

// WT2[k][col] = (W_ih[col][k], W_hh[col][k]) as float2, col in [0,768)
__global__ __launch_bounds__(256) void prep2_k(const float* __restrict__ W_ih,
                                               const float* __restrict__ W_hh,
                                               float2* __restrict__ WT2) {
  int col = blockIdx.x;      // 0..767
  int k = threadIdx.x;       // 0..255
  WT2[(size_t)k * 768 + col] =
      make_float2(W_ih[(size_t)col * 256 + k], W_hh[(size_t)col * 256 + k]);
}

__device__ __forceinline__ float waveRed(float v) {
  v += __shfl_down(v, 32, 64);
  v += __shfl_down(v, 16, 64);
  v += __shfl_down(v, 8, 64);
  v += __shfl_down(v, 4, 64);
  v += __shfl_down(v, 2, 64);
  v += __shfl_down(v, 1, 64);
  return v;
}

__global__ __launch_bounds__(256) void bx_k(const float* __restrict__ obs,
                                            const float* __restrict__ W_beta,
                                            const float* __restrict__ b_beta,
                                            float* __restrict__ bxv) {
  int m = blockIdx.x, tid = threadIdx.x;
  const float* row = obs + (size_t)m * CONV;
  float p0 = 0.f, p1 = 0.f;
  for (int i = tid; i < CONV; i += 256) {
    float o = row[i];
    p0 = fmaf(o, W_beta[i], p0);
    p1 = fmaf(o, W_beta[LDWB + i], p1);
  }
  p0 = waveRed(p0); p1 = waveRed(p1);
  __shared__ float sc[2][4];
  int w = tid >> 6;
  if ((tid & 63) == 0) { sc[0][w] = p0; sc[1][w] = p1; }
  __syncthreads();
  if (tid == 0) bxv[(size_t)m * 2 + 0] = sc[0][0] + sc[0][1] + sc[0][2] + sc[0][3] + b_beta[0];
  if (tid == 1) bxv[(size_t)m * 2 + 1] = sc[1][0] + sc[1][1] + sc[1][2] + sc[1][3] + b_beta[1];
}

// ------------------------------- big GEMM ----------------------------------
// C1[m][n] = obs[m] . W_f[n][:4096] + b_f[n]   (M=32768, N=256, K=4096)
struct __attribute__((packed, aligned(4))) F4 { float x, y, z, w; };

__global__ __launch_bounds__(256) void gemm1_k(const float* __restrict__ A,
                                               const float* __restrict__ W,
                                               const float* __restrict__ bias,
                                               float* __restrict__ C1) {
  __shared__ __align__(16) float As[32][68];
  __shared__ __align__(16) float Bs[32][68];
  int bid = blockIdx.x;
  int mt = bid & 511, nt = bid >> 9;
  int m0 = mt * 64, n0 = nt * 64;
  int tid = threadIdx.x;
  int tm = tid & 15, tn = tid >> 4;
  int lr = tid >> 2;
  int lc = (tid & 3) * 8;
  float acc[4][4] = {};
  for (int k0 = 0; k0 < CONV; k0 += 32) {
    F4 a0 = *(const F4*)(A + (size_t)(m0 + lr) * CONV + k0 + lc);
    F4 a1 = *(const F4*)(A + (size_t)(m0 + lr) * CONV + k0 + lc + 4);
    F4 b0 = *(const F4*)(W + (size_t)(n0 + lr) * LDWF + k0 + lc);
    F4 b1 = *(const F4*)(W + (size_t)(n0 + lr) * LDWF + k0 + lc + 4);
    __syncthreads();
    As[lc + 0][lr] = a0.x; As[lc + 1][lr] = a0.y; As[lc + 2][lr] = a0.z; As[lc + 3][lr] = a0.w;
    As[lc + 4][lr] = a1.x; As[lc + 5][lr] = a1.y; As[lc + 6][lr] = a1.z; As[lc + 7][lr] = a1.w;
    Bs[lc + 0][lr] = b0.x; Bs[lc + 1][lr] = b0.y; Bs[lc + 2][lr] = b0.z; Bs[lc + 3][lr] = b0.w;
    Bs[lc + 4][lr] = b1.x; Bs[lc + 5][lr] = b1.y; Bs[lc + 6][lr] = b1.z; Bs[lc + 7][lr] = b1.w;
    __syncthreads();
#pragma unroll
    for (int kk = 0; kk < 32; ++kk) {
      const float4 av = *(const float4*)&As[kk][tm * 4];
      const float4 bv = *(const float4*)&Bs[kk][tn * 4];
      acc[0][0] = fmaf(av.x, bv.x, acc[0][0]); acc[0][1] = fmaf(av.x, bv.y, acc[0][1]);
      acc[0][2] = fmaf(av.x, bv.z, acc[0][2]); acc[0][3] = fmaf(av.x, bv.w, acc[0][3]);
      acc[1][0] = fmaf(av.y, bv.x, acc[1][0]); acc[1][1] = fmaf(av.y, bv.y, acc[1][1]);
      acc[1][2] = fmaf(av.y, bv.z, acc[1][2]); acc[1][3] = fmaf(av.y, bv.w, acc[1][3]);
      acc[2][0] = fmaf(av.z, bv.x, acc[2][0]); acc[2][1] = fmaf(av.z, bv.y, acc[2][1]);
      acc[2][2] = fmaf(av.z, bv.z, acc[2][2]); acc[2][3] = fmaf(av.z, bv.w, acc[2][3]);
      acc[3][0] = fmaf(av.w, bv.x, acc[3][0]); acc[3][1] = fmaf(av.w, bv.y, acc[3][1]);
      acc[3][2] = fmaf(av.w, bv.z, acc[3][2]); acc[3][3] = fmaf(av.w, bv.w, acc[3][3]);
    }
  }
  const int mrow = m0 + tm * 4;
  const int ncol = n0 + tn * 4;
  float4 bv4 = *(const float4*)(bias + ncol);
#pragma unroll
  for (int i = 0; i < 4; ++i) {
    float4 v;
    v.x = acc[i][0] + bv4.x; v.y = acc[i][1] + bv4.y;
    v.z = acc[i][2] + bv4.z; v.w = acc[i][3] + bv4.w;
    *(float4*)(C1 + (size_t)(mrow + i) * 256 + ncol) = v;
  }
}

// ------------------------------ sequential ---------------------------------
// One block (768 threads, 12 waves) per batch row. No grid sync.
__global__ __launch_bounds__(768, 1) void seq_k(
    const float* __restrict__ hx0, const float* __restrict__ task,
    const float* __restrict__ W_f, const float* __restrict__ WT2,
    const float* __restrict__ b_ih, const float* __restrict__ b_hh,
    const float* __restrict__ W_u, const float* __restrict__ b_u,
    const float* __restrict__ W_s, const float* __restrict__ b_s,
    const float* __restrict__ W_pi, const float* __restrict__ b_pi,
    const float* __restrict__ W_beta, const float* __restrict__ C1,
    const float* __restrict__ bxv, const float* __restrict__ ggum,
    const float* __restrict__ bgum, float* __restrict__ out) {
  const int b = blockIdx.x;
  const int tid = threadIdx.x;   // 0..767
  const int o = tid & 255;
  const int part = tid >> 8;     // 0: r-pair, 1: z-pair, 2: n-pair
  const float2* __restrict__ WT2v = (const float2*)WT2;

  __shared__ float wf_sh[65 * 256];      // wf_sh[o*65+j] = W_f[o][CONV+j]  (66 KB)
  __shared__ float wpi_sh[288 * 16];     // wpi_sh[o2*288+j] = W_pi[o2][j]  (18 KB)
  __shared__ float2 shb[256];            // (s, h)
  __shared__ float2 gsum[2][256];        // z-pair, n-pair
  __shared__ float M_sh[512];
  __shared__ float p_sh[16], pn_sh[16], r_sh[32], g_sh[32];
  __shared__ float red4[4][4];
  __shared__ float red16[4][16];
  __shared__ float logit_sh[16];
  __shared__ float l_sh[3];
  __shared__ float c_sh, b_sh;
  __shared__ int gidx_sh;
  __shared__ float misc_sh[3];           // 0: lp_g, 1: b', 2: lp_total
  __shared__ float gg_sh[16], bg_sh[2], bx_sh[2];
  __shared__ float wb_sh[2][32], bpi_sh[16];

  // ---- one-time init ----
  // wf_sh[o*65+j] = W_f[o*LDWF + CONV + j]
  for (int i = tid; i < 65 * 256; i += 768) {
    int oo = i / 65, j = i % 65;
    wf_sh[i] = W_f[(size_t)oo * LDWF + CONV + j];
  }
  for (int i = tid; i < 288 * 16; i += 768) wpi_sh[i] = W_pi[i];
  if (part == 0) shb[o] = make_float2(0.f, hx0[b * TOT + 48 + o]);
  if (tid < 16) p_sh[tid] = hx0[b * TOT + tid];
  if (tid < 32) {
    r_sh[tid] = hx0[b * TOT + 16 + tid];
    g_sh[tid] = hx0[b * TOT + 304 + tid];
    wb_sh[0][tid] = W_beta[CONV + tid];
    wb_sh[1][tid] = W_beta[LDWB + CONV + tid];
  }
  if (tid >= 32 && tid < 48) bpi_sh[tid - 32] = b_pi[tid - 32];
  if (tid == 0) b_sh = hx0[b * TOT + 336];
  if (tid < 512) M_sh[tid] = task[(size_t)b * 512 + tid];

  // per-thread constants (indexed by o; used by part0)
  const float bih_r = b_ih[o], bih_z = b_ih[256 + o], bih_n = b_ih[512 + o];
  const float bhh_r = b_hh[o], bhh_z = b_hh[256 + o], bhh_n = b_hh[512 + o];
  const float wu_s = W_u[o], wu_h = W_u[256 + o];
  const float ws0 = W_s[o], ws1 = W_s[256 + o], ws2 = W_s[512 + o];
  const float bu0 = b_u[0], bs0 = b_s[0], bs1 = b_s[1], bs2 = b_s[2];
  __syncthreads();

  float c1v = (part == 0) ? C1[(size_t)b * 256 + o] : 0.f;   // t=0 row
  float sacc = 0.f, hold = 0.f;

  for (int t = 0; t < T_STEPS; ++t) {
    // ---- Phase 1 (part0): s = C1 row + W_f tail over [r, g, b] ----
    if (part == 0) {
      hold = shb[o].y;
      sacc = c1v;
      const float* wfr = wf_sh + o * 65;
#pragma unroll
      for (int j = 0; j < 32; ++j) sacc = fmaf(r_sh[j], wfr[j], sacc);
#pragma unroll
      for (int j = 0; j < 32; ++j) sacc = fmaf(g_sh[j], wfr[32 + j], sacc);
      sacc = fmaf(b_sh, wfr[64], sacc);
      shb[o].x = sacc;
    }
    __syncthreads();                                           // S1: s published

    // prefetches (latency hidden under the stream)
    if (part == 0) {
      int tn2 = (t + 1 < T_STEPS) ? t + 1 : t;
      c1v = C1[((size_t)tn2 * 256 + b) * 256 + o];
    } else if (tid < 272) {
      gg_sh[tid - 256] = ggum[((size_t)t * 256 + b) * 16 + (tid - 256)];
    } else if (tid < 274) {
      bg_sh[tid - 272] = bgum[((size_t)t * 256 + b) * 2 + (tid - 272)];
    } else if (tid < 276) {
      bx_sh[tid - 274] = bxv[((size_t)t * 256 + b) * 2 + (tid - 274)];
    }

    // ---- Phase 2: main packed stream (all 768 threads) ----
    float ai = 0.f, ah = 0.f;
#pragma unroll 8
    for (int k = 0; k < 256; ++k) {
      float2 w = WT2v[(size_t)k * 768 + tid];
      float2 sh2 = shb[k];
      ai = fmaf(sh2.x, w.x, ai);
      ah = fmaf(sh2.y, w.y, ah);
    }
    if (part == 0) {
      // c/l partials (verbatim R3 order)
      float pc = fmaf(wu_s, sacc, wu_h * hold);
      float q0 = ws0 * hold, q1 = ws1 * hold, q2 = ws2 * hold;
      pc = waveRed(pc); q0 = waveRed(q0); q1 = waveRed(q1); q2 = waveRed(q2);
      int w4 = tid >> 6;
      if ((tid & 63) == 0) { red4[w4][0] = pc; red4[w4][1] = q0; red4[w4][2] = q1; red4[w4][3] = q2; }
    } else {
      gsum[part - 1][o] = make_float2(ai, ah);
    }
    __syncthreads();                                           // S2
    if (tid == 0) {
      float cs = red4[0][0] + red4[1][0] + red4[2][0] + red4[3][0] + bu0;
      c_sh = 1.0f / (1.0f + expf(-cs));
      float x0 = red4[0][1] + red4[1][1] + red4[2][1] + red4[3][1] + bs0;
      float x1 = red4[0][2] + red4[1][2] + red4[2][2] + red4[3][2] + bs1;
      float x2 = red4[0][3] + red4[1][3] + red4[2][3] + red4[3][3] + bs2;
      float m = fmaxf(x0, fmaxf(x1, x2));
      float e0 = expf(x0 - m), e1 = expf(x1 - m), e2 = expf(x2 - m);
      float es = e0 + e1 + e2;
      l_sh[0] = e0 / es; l_sh[1] = e1 / es; l_sh[2] = e2 / es;
    }
    __syncthreads();                                           // S3: c, l ready
    const float c = c_sh, omc = 1.0f - c;
    float hg = 0.f;
    if (part == 0) {
      float2 gz = gsum[0][o];   // (gi_z, gh_z)
      float2 gn = gsum[1][o];   // (gi_n, gh_n)
      float rr = 1.0f / (1.0f + expf(-(ai + bih_r + ah + bhh_r)));
      float zz = 1.0f / (1.0f + expf(-(gz.x + bih_z + gz.y + bhh_z)));
      float nn = tanhf(gn.x + bih_n + rr * (gn.y + bhh_n));
      float hnew = (1.0f - zz) * nn + zz * hold;
      hg = c * hnew + omc * hold;
      shb[o].y = hg;
    }
    if (tid < 16) {
      float pm1 = (tid > 0) ? p_sh[tid - 1] : 0.f;
      float pp1 = (tid < 15) ? p_sh[tid + 1] : 0.f;
      pn_sh[tid] = l_sh[0] * pm1 + l_sh[1] * p_sh[tid] + l_sh[2] * pp1;
    }
    __syncthreads();                                           // S4: h', p_new ready
    float rv = 0.f;
    if (tid < 32) {
      float acc = 0.f;
#pragma unroll
      for (int n2 = 0; n2 < 16; ++n2) acc = fmaf(pn_sh[n2], M_sh[n2 * 32 + tid], acc);
      rv = c * acc + omc * r_sh[tid];
      r_sh[tid] = rv;
    }
    if (tid < 16) p_sh[tid] = c * pn_sh[tid] + omc * p_sh[tid];
    // logits_g = [h', r'] @ W_pi^T + b_pi  (part0 only; verbatim R3 order)
    if (part == 0) {
      float pv[16];
#pragma unroll
      for (int o2 = 0; o2 < 16; ++o2) pv[o2] = hg * wpi_sh[o2 * 288 + tid];
      if (tid < 32) {
#pragma unroll
        for (int o2 = 0; o2 < 16; ++o2) pv[o2] = fmaf(rv, wpi_sh[o2 * 288 + 256 + tid], pv[o2]);
      }
#pragma unroll
      for (int o2 = 0; o2 < 16; ++o2) pv[o2] = waveRed(pv[o2]);
      int w4 = tid >> 6;
      if ((tid & 63) == 0) {
#pragma unroll
        for (int o2 = 0; o2 < 16; ++o2) red16[w4][o2] = pv[o2];
      }
    }
    __syncthreads();                                           // S5
    if (tid < 16)
      logit_sh[tid] = red16[0][tid] + red16[1][tid] + red16[2][tid] + red16[3][tid] + bpi_sh[tid];
    __syncthreads();                                           // S6
    if (tid == 0) {
      float best = -3.402823466e+38f; int gidx = 0;
      for (int n2 = 0; n2 < 16; ++n2) {
        float v = logit_sh[n2] + gg_sh[n2];
        if (v > best) { best = v; gidx = n2; }
      }
      float mx = logit_sh[0];
      for (int n2 = 1; n2 < 16; ++n2) mx = fmaxf(mx, logit_sh[n2]);
      float se = 0.f;
      for (int n2 = 0; n2 < 16; ++n2) se += expf(logit_sh[n2] - mx);
      misc_sh[0] = logit_sh[gidx] - mx - logf(se);
      gidx_sh = gidx;
    }
    __syncthreads();                                           // S7
    if (tid < 32) g_sh[tid] = c * M_sh[gidx_sh * 32 + tid] + omc * g_sh[tid];
    __syncthreads();                                           // S8
    if (tid == 0) {
      float lb0 = bx_sh[0], lb1 = bx_sh[1];
      for (int s2 = 0; s2 < 32; ++s2) {
        float gv = g_sh[s2];
        lb0 = fmaf(gv, wb_sh[0][s2], lb0);
        lb1 = fmaf(gv, wb_sh[1][s2], lb1);
      }
      int bidx = ((lb1 + bg_sh[1]) > (lb0 + bg_sh[0])) ? 1 : 0;
      float mb = fmaxf(lb0, lb1);
      float seb = expf(lb0 - mb) + expf(lb1 - mb);
      float lpb = (bidx ? lb1 : lb0) - mb - logf(seb);
      misc_sh[1] = (float)bidx;
      misc_sh[2] = misc_sh[0] + lpb;
      b_sh = (float)bidx;
    }
    __syncthreads();                                           // S9
    // ---- outputs: [p16, r32, h256, g32, b1, lp1] ----
    if (tid < TOT) {
      size_t base = ((size_t)t * 256 + b) * TOT;
      float v;
      if (tid < 16) v = p_sh[tid];
      else if (tid < 48) v = r_sh[tid - 16];
      else if (tid < 304) v = shb[tid - 48].y;
      else if (tid < 336) v = g_sh[tid - 304];
      else if (tid == 336) v = misc_sh[1];
      else v = misc_sh[2];
      out[base + tid] = v;
    }
    __syncthreads();                                           // S10: out reads done
  }
}

// ------------------------------ host launch --------------------------------
extern "C" void kernel_launch(void* const* d_in, const int* in_sizes, int n_in,
                              void* d_out, int out_size, void* d_ws, size_t ws_size,
                              hipStream_t stream) {
  const float* obs    = (const float*)d_in[0];
  const float* task   = (const float*)d_in[1];
  const float* hx0    = (const float*)d_in[2];
  const float* W_ih   = (const float*)d_in[3];
  const float* W_hh   = (const float*)d_in[4];
  const float* b_ih   = (const float*)d_in[5];
  const float* b_hh   = (const float*)d_in[6];
  const float* W_f    = (const float*)d_in[7];
  const float* b_f    = (const float*)d_in[8];
  const float* W_u    = (const float*)d_in[9];
  const float* b_u    = (const float*)d_in[10];
  const float* W_s    = (const float*)d_in[11];
  const float* b_s    = (const float*)d_in[12];
  const float* W_pi   = (const float*)d_in[13];
  const float* b_pi   = (const float*)d_in[14];
  const float* W_beta = (const float*)d_in[15];
  const float* b_beta = (const float*)d_in[16];

  char* ws = (char*)d_ws;
  size_t off = 0;
  auto take = [&](size_t bytes) {
    size_t r = off;
    off += (bytes + 255) & ~(size_t)255;
    return r;
  };
  size_t off_WT2  = take((size_t)768 * 256 * 8);
  size_t off_ggum = take((size_t)T_STEPS * B_ROWS * 16 * 4);
  size_t off_bgum = take((size_t)T_STEPS * B_ROWS * 2 * 4);
  size_t off_bx   = take((size_t)T_STEPS * B_ROWS * 2 * 4);
  size_t off_C1   = take((size_t)T_STEPS * B_ROWS * 256 * 4);
  if (off > ws_size) return;

  float* WT2  = (float*)(ws + off_WT2);
  float* ggum = (float*)(ws + off_ggum);
  float* bgum = (float*)(ws + off_bgum);
  float* bxv  = (float*)(ws + off_bx);
  float* C1   = (float*)(ws + off_C1);

  hipLaunchKernelGGL(prep2_k, dim3(768), dim3(256), 0, stream, W_ih, W_hh, (float2*)WT2);
  hipLaunchKernelGGL(rng_k, dim3(2304), dim3(256), 0, stream, ggum, bgum);
  hipLaunchKernelGGL(gemm1_k, dim3(2048), dim3(256), 0, stream, obs, W_f, b_f, C1);
  hipLaunchKernelGGL(bx_k, dim3(32768), dim3(256), 0, stream, obs, W_beta, b_beta, bxv);
  hipLaunchKernelGGL(seq_k, dim3(256), dim3(768), 0, stream,
                     hx0, task, W_f, WT2, b_ih, b_hh, W_u, b_u, W_s, b_s, W_pi, b_pi,
                     W_beta, C1, bxv, ggum, bgum, (float*)d_out);
}